// Round 1
// baseline (172.131 us; speedup 1.0000x reference)
//
#include <hip/hip_runtime.h>
#include <math.h>

#define D_MODEL   2048
#define N_EXPERTS 64
#define TOP_K     8
#define N_TOKENS  16384

#define TOK_TILE  64
#define KC        32
#define NTHREADS  512
#define EXP_PER_WAVE 8   // 64 experts / 8 waves

__global__ __launch_bounds__(NTHREADS) void router_kernel(
    const float* __restrict__ x, const float* __restrict__ gw,
    float* __restrict__ out)
{
    __shared__ float xs[TOK_TILE][KC + 1];    // +1 pad: 2-way conflicts only (free)
    __shared__ float wsh[N_EXPERTS][KC + 4];  // +4 pad keeps float4 alignment
    __shared__ float lt[TOK_TILE][N_EXPERTS + 1];
    __shared__ float smax[TOK_TILE], srs[TOK_TILE];

    const int tid  = threadIdx.x;
    const int lane = tid & 63;         // token within tile
    const int wv   = tid >> 6;         // wave id 0..7
    const int m0   = blockIdx.x * TOK_TILE;

    // cooperative staging coords: 64 rows x (KC=32) floats = 512 float4, 512 thr
    const int srow = tid >> 3;         // 0..63
    const int skq  = (tid & 7) * 4;    // 0,4,...,28

    const float* xsrc = x  + (size_t)(m0 + srow) * D_MODEL + skq;
    const float* wsrc = gw + (size_t)srow       * D_MODEL + skq;

    // prefetch chunk 0
    float4 xr = *(const float4*)(xsrc);
    float4 wr = *(const float4*)(wsrc);

    float acc[EXP_PER_WAVE];
#pragma unroll
    for (int i = 0; i < EXP_PER_WAVE; ++i) acc[i] = 0.f;

    const int e0 = wv * EXP_PER_WAVE;
    const int NCHUNK = D_MODEL / KC;

    for (int c = 0; c < NCHUNK; ++c) {
        // write staged registers to LDS
        xs[srow][skq + 0] = xr.x;
        xs[srow][skq + 1] = xr.y;
        xs[srow][skq + 2] = xr.z;
        xs[srow][skq + 3] = xr.w;
        *(float4*)&wsh[srow][skq] = wr;
        __syncthreads();

        // issue next chunk's global loads early (latency hides under compute)
        if (c + 1 < NCHUNK) {
            xr = *(const float4*)(xsrc + (c + 1) * KC);
            wr = *(const float4*)(wsrc + (c + 1) * KC);
        }

#pragma unroll
        for (int k4 = 0; k4 < KC / 4; ++k4) {
            const float xv0 = xs[lane][k4 * 4 + 0];
            const float xv1 = xs[lane][k4 * 4 + 1];
            const float xv2 = xs[lane][k4 * 4 + 2];
            const float xv3 = xs[lane][k4 * 4 + 3];
#pragma unroll
            for (int e = 0; e < EXP_PER_WAVE; ++e) {
                const float4 w4 = *(const float4*)&wsh[e0 + e][k4 * 4];
                acc[e] = fmaf(xv0, w4.x, acc[e]);
                acc[e] = fmaf(xv1, w4.y, acc[e]);
                acc[e] = fmaf(xv2, w4.z, acc[e]);
                acc[e] = fmaf(xv3, w4.w, acc[e]);
            }
        }
        __syncthreads();
    }

    // scatter accumulators into logits tile
#pragma unroll
    for (int e = 0; e < EXP_PER_WAVE; ++e) lt[lane][e0 + e] = acc[e];
    __syncthreads();

    float* out_idx = out;
    float* out_w   = out + (size_t)N_TOKENS * TOP_K;
    float* out_p   = out + (size_t)2 * N_TOKENS * TOP_K;
    float* out_l   = out_p + (size_t)N_TOKENS * N_EXPERTS;

    if (tid < TOK_TILE) {
        const int t = tid;
        float tv[TOP_K];
        int   ti[TOP_K];
#pragma unroll
        for (int i = 0; i < TOP_K; ++i) { tv[i] = -INFINITY; ti[i] = 0; }
        float m = -INFINITY;

        for (int e = 0; e < N_EXPERTS; ++e) {
            const float v = lt[t][e];
            m = fmaxf(m, v);
            // branch-free sorted insert, all-static indexing (no scratch)
            const bool beat_last = (v > tv[TOP_K - 1]);
            if (beat_last) {
#pragma unroll
                for (int j = TOP_K - 1; j >= 1; --j) {
                    const bool shift = (v > tv[j - 1]);
                    const bool here  = (v > tv[j]);
                    const float ntv = shift ? tv[j - 1] : (here ? v : tv[j]);
                    const int   nti = shift ? ti[j - 1] : (here ? e : ti[j]);
                    tv[j] = ntv; ti[j] = nti;
                }
                if (v > tv[0]) { tv[0] = v; ti[0] = e; }
            }
        }

        float s = 0.f;
        for (int e = 0; e < N_EXPERTS; ++e) s += expf(lt[t][e] - m);
        const float rs = 1.f / s;
        smax[t] = m;
        srs[t]  = rs;

        // softmax over the top-8 logits (tv[0] is the max)
        float ex[TOP_K];
        float wsum = 0.f;
#pragma unroll
        for (int i = 0; i < TOP_K; ++i) { ex[i] = expf(tv[i] - tv[0]); wsum += ex[i]; }
        const float rw = 1.f / wsum;

        const int tok = m0 + t;
#pragma unroll
        for (int i = 0; i < TOP_K; ++i) {
            out_idx[(size_t)tok * TOP_K + i] = (float)ti[i];
            out_w  [(size_t)tok * TOP_K + i] = ex[i] * rw;
        }
    }
    __syncthreads();

    // cooperative coalesced float4 writes of full_probs and logits
#pragma unroll
    for (int rep = 0; rep < 2; ++rep) {
        const int f = rep * (NTHREADS * 4) + tid * 4;   // 0..4092, step 4
        const int t = f >> 6;
        const int e = f & 63;
        const float l0 = lt[t][e + 0];
        const float l1 = lt[t][e + 1];
        const float l2 = lt[t][e + 2];
        const float l3 = lt[t][e + 3];
        const float mm = smax[t];
        const float rr = srs[t];
        float4 pv = make_float4(expf(l0 - mm) * rr, expf(l1 - mm) * rr,
                                expf(l2 - mm) * rr, expf(l3 - mm) * rr);
        float4 lv = make_float4(l0, l1, l2, l3);
        const size_t gbase = (size_t)m0 * N_EXPERTS + f;
        *(float4*)(out_p + gbase) = pv;
        *(float4*)(out_l + gbase) = lv;
    }
}

extern "C" void kernel_launch(void* const* d_in, const int* in_sizes, int n_in,
                              void* d_out, int out_size, void* d_ws, size_t ws_size,
                              hipStream_t stream) {
    const float* x  = (const float*)d_in[0];
    const float* gw = (const float*)d_in[1];
    float* out = (float*)d_out;
    router_kernel<<<dim3(N_TOKENS / TOK_TILE), dim3(NTHREADS), 0, stream>>>(x, gw, out);
}